// Round 16
// baseline (102.302 us; speedup 1.0000x reference)
//
#include <hip/hip_runtime.h>
#include <hip/hip_bf16.h>
#include <stdint.h>

#define D 128
#define BKT_W 16             // nodes per bucket
#define BKT_SH 4
#define NB_MAX 2048          // supports N <= 32768
#define RPB 128              // rows per block in MFMA h-GEMM
#define CAPMAX 1024          // per-bucket record capacity (uint32 each)
#define EPT2 32              // edges per thread in 2-pass partition (8192/block)

typedef __attribute__((ext_vector_type(8))) short bf16x8;
typedef __attribute__((ext_vector_type(4))) float f32x4;

static __device__ __forceinline__ short f2bf(float x) {
    __hip_bfloat16 h = __float2bfloat16(x);
    return *reinterpret_cast<short*>(&h);
}

// ---------------- W pre-pack into MFMA B-fragment order (+ zero bucket cursors) ----------------
__global__ __launch_bounds__(256) void pack_w_k(const float* __restrict__ W0,
                                                const float* __restrict__ W1,
                                                const float* __restrict__ W2,
                                                short* __restrict__ P0,
                                                short* __restrict__ P1,
                                                short* __restrict__ P2,
                                                int* __restrict__ bcur, int nb2) {
    if (blockIdx.x == 0) {
        for (int i = threadIdx.x; i < nb2; i += 256) bcur[i] = 0;
    }
    int t = blockIdx.x * 256 + threadIdx.x;      // 3 * 2048 threads
    int m = t >> 11;
    int r = t & 2047;                            // (kc*8+ct)*64 + lane
    const float* W = (m == 0) ? W0 : (m == 1) ? W1 : W2;
    short*       P = (m == 0) ? P0 : (m == 1) ? P1 : P2;
    int lane = r & 63;
    int fr   = r >> 6;                           // kc*8 + ct
    int kc = fr >> 3, ct = fr & 7;
    int col = ct * 16 + (lane & 15);
    int kb  = kc * 32 + 4 * (lane >> 4);
    short v[8];
#pragma unroll
    for (int e = 0; e < 8; ++e) {
        int k = kb + (e & 3) + 16 * (e >> 2);
        v[e] = f2bf(W[k * D + col]);
    }
    short* dst = P + (size_t)r * 8;
#pragma unroll
    for (int e = 0; e < 8; ++e) dst[e] = v[e];
}

// ---------------- FAT kernel: MFMA h-GEMM (2*mg blocks) || 2-pass edge partition ----------------
__global__ __launch_bounds__(256) void fat_h_part_k(
    const float* __restrict__ IN0, const float* __restrict__ IN1,
    const short* __restrict__ P0,  const short* __restrict__ P1,
    short* __restrict__ HB0, short* __restrict__ HB1,
    const float* __restrict__ as0, const float* __restrict__ as1,
    const float* __restrict__ ad0, const float* __restrict__ ad1,
    float* __restrict__ ss0, float* __restrict__ ss1,
    float* __restrict__ sd0, float* __restrict__ sd1,
    int nrows, int mg,
    const int* __restrict__ esrc, const int* __restrict__ edst,
    int* __restrict__ bcur_d, int* __restrict__ bcur_s,
    uint32_t* __restrict__ rec_d, uint32_t* __restrict__ rec_s,
    int ne, int cap) {
    __shared__ __align__(16) char smem[RPB * 136 * 2];
    int bid = blockIdx.x;
    int tid = threadIdx.x;

    if (bid < 2 * mg) {
        // ---------- MFMA h-GEMM branch ----------
        int yy = (bid >= mg) ? 1 : 0;
        int xb = bid - yy * mg;
        const float* IN = yy ? IN1 : IN0;
        const short* PK = yy ? P1  : P0;
        short*       HB = yy ? HB1 : HB0;
        const float* a_src = yy ? as1 : as0;
        const float* a_dst = yy ? ad1 : ad0;
        float* ss = yy ? ss1 : ss0;
        float* sd = yy ? sd1 : sd0;
        short* As = (short*)smem;

        int row0 = xb * RPB;
        const float4* in4 = (const float4*)IN;
#pragma unroll
        for (int i = 0; i < 16; ++i) {
            int idx = tid + i * 256;
            int row = idx >> 5;               // 32 float4 per row
            int q   = idx & 31;
            float4 v = make_float4(0.f, 0.f, 0.f, 0.f);
            int grow = row0 + row;
            if (grow < nrows) v = in4[(size_t)grow * 32 + q];
            int kc = q >> 3, hi = (q >> 2) & 1, g2 = q & 3;
            short4 s4;
            s4.x = f2bf(v.x); s4.y = f2bf(v.y); s4.z = f2bf(v.z); s4.w = f2bf(v.w);
            *(short4*)&As[row * 136 + kc * 32 + g2 * 8 + hi * 4] = s4;
        }
        __syncthreads();

        int lane = tid & 63;
        int wv   = tid >> 6;
        const bf16x8* Wf = (const bf16x8*)PK;
        f32x4 acc[2][8] = {};
#pragma unroll
        for (int kc = 0; kc < 4; ++kc) {
            bf16x8 a0 = *(const bf16x8*)&As[(wv * 32 +      (lane & 15)) * 136 + kc * 32 + (lane >> 4) * 8];
            bf16x8 a1 = *(const bf16x8*)&As[(wv * 32 + 16 + (lane & 15)) * 136 + kc * 32 + (lane >> 4) * 8];
#pragma unroll
            for (int ct = 0; ct < 8; ++ct) {
                bf16x8 b = Wf[(kc * 8 + ct) * 64 + lane];
                acc[0][ct] = __builtin_amdgcn_mfma_f32_16x16x32_bf16(a0, b, acc[0][ct], 0, 0, 0);
                acc[1][ct] = __builtin_amdgcn_mfma_f32_16x16x32_bf16(a1, b, acc[1][ct], 0, 0, 0);
            }
        }

        int cb = lane & 15, rg = lane >> 4;
        float asv[8], adv[8];
#pragma unroll
        for (int ct = 0; ct < 8; ++ct) { asv[ct] = a_src[ct * 16 + cb]; adv[ct] = a_dst[ct * 16 + cb]; }
#pragma unroll
        for (int rt = 0; rt < 2; ++rt) {
            float ssum[4] = {0, 0, 0, 0}, dsum[4] = {0, 0, 0, 0};
#pragma unroll
            for (int ct = 0; ct < 8; ++ct) {
#pragma unroll
                for (int r = 0; r < 4; ++r) {
                    float x = acc[rt][ct][r];
                    int grow = row0 + wv * 32 + rt * 16 + rg * 4 + r;
                    if (grow < nrows) HB[(size_t)grow * D + ct * 16 + cb] = f2bf(x);
                    ssum[r] += x * asv[ct];
                    dsum[r] += x * adv[ct];
                }
            }
#pragma unroll
            for (int off = 1; off < 16; off <<= 1) {
#pragma unroll
                for (int r = 0; r < 4; ++r) {
                    ssum[r] += __shfl_xor(ssum[r], off);
                    dsum[r] += __shfl_xor(dsum[r], off);
                }
            }
            if (cb == 0) {
#pragma unroll
                for (int r = 0; r < 4; ++r) {
                    int grow = row0 + wv * 32 + rt * 16 + rg * 4 + r;
                    if (grow < nrows) { ss[grow] = ssum[r]; sd[grow] = dsum[r]; }
                }
            }
        }
    } else {
        // ---------- 2-pass edge partition branch (8192 edges/block, low VGPR) ----------
        int pid = bid - 2 * mg;
        int* cnt  = (int*)smem;                       // [2][NB_MAX] = 16KB
        int* base = (int*)(smem + 2 * NB_MAX * 4);    // [2][NB_MAX] = 16KB (becomes cursor)
        int blockStart = pid * 256 * EPT2;
        for (int i = tid; i < 2 * NB_MAX; i += 256) cnt[i] = 0;
        __syncthreads();
        // pass 1: count
        for (int e = 0; e < EPT2; ++e) {
            int i = blockStart + e * 256 + tid;
            if (i < ne) {
                atomicAdd(&cnt[0 * NB_MAX + (edst[i] >> BKT_SH)], 1);
                atomicAdd(&cnt[1 * NB_MAX + (esrc[i] >> BKT_SH)], 1);
            }
        }
        __syncthreads();
        // reserve global runs; base becomes per-bucket cursor
        for (int i = tid; i < 2 * NB_MAX; i += 256) {
            int a = (i < NB_MAX) ? i : i - NB_MAX;
            int cv = cnt[i];
            base[i] = cv ? ((i < NB_MAX) ? atomicAdd(&bcur_d[a], cv)
                                         : atomicAdd(&bcur_s[a], cv)) : 0;
        }
        __syncthreads();
        // pass 2: re-read edges, write records at cursor positions
        for (int e = 0; e < EPT2; ++e) {
            int i = blockStart + e * 256 + tid;
            if (i < ne) {
                int s = esrc[i], d = edst[i];
                int bd = d >> BKT_SH, bs = s >> BKT_SH;
                int od = atomicAdd(&base[0 * NB_MAX + bd], 1);
                int os = atomicAdd(&base[1 * NB_MAX + bs], 1);
                if (od < cap) rec_d[(size_t)bd * cap + od] = (uint32_t)s | ((uint32_t)(d & (BKT_W - 1)) << 17);
                if (os < cap) rec_s[(size_t)bs * cap + os] = (uint32_t)d | ((uint32_t)(s & (BKT_W - 1)) << 17);
            }
        }
    }
}

// ---------------- FUSED bucket sort + weights + gather + epilogue GEMM ----------------
// One block per (bucket of 16 nodes, dir), 256 thr = 4 waves. Phase A: LDS sort + weight calc.
// Phase B: each wave gathers 4 nodes, 32 edges/iter (8 uint4 in flight). Phase C: MFMA epilogue.
__global__ __launch_bounds__(256) void bucket_gat_ep_k(
    const uint32_t* __restrict__ rec_d, const uint32_t* __restrict__ rec_s,
    const int* __restrict__ bcur_d, const int* __restrict__ bcur_s,
    const float* __restrict__ ss1, const float* __restrict__ sd1,
    const float* __restrict__ ss2, const float* __restrict__ sd2,
    const short* __restrict__ hb1, const short* __restrict__ hb2,
    const float* __restrict__ b1,  const float* __restrict__ b2,
    const float* __restrict__ Xw,  const float* __restrict__ Xs,
    const short* __restrict__ wpkL, const float* __restrict__ b_lin,
    float* __restrict__ out, int n, int nb, int cap) {

    __shared__ __align__(16) short T[BKT_W * 136];           // 4.35KB frag tile
    __shared__ uint32_t srec[CAPMAX];                        // 4KB sorted weighted records
    __shared__ uint32_t lrec[CAPMAX];                        // 4KB raw staging
    __shared__ int deg[BKT_W], scn[BKT_W], cur[BKT_W];
    __shared__ float sdl[BKT_W];

    int bid = blockIdx.x;
    int dirv = (bid >= nb) ? 1 : 0;
    int b = bid - dirv * nb;
    const uint32_t* rec  = dirv ? rec_s  : rec_d;
    const int*      bc   = dirv ? bcur_s : bcur_d;
    const float*    ss   = dirv ? ss2 : ss1;      // neighbor-side score
    const float*    sv   = dirv ? sd2 : sd1;      // self-side score
    const short*    hb   = dirv ? hb2 : hb1;
    const float*    bias = dirv ? b2  : b1;
    const float*    resid= dirv ? Xs  : Xw;
    float*          outp = out + (size_t)dirv * n * D;

    int tid = threadIdx.x;
    int cnt = bc[b]; if (cnt > cap) cnt = cap;
    size_t base = (size_t)b * cap;

    // ---- Phase A: stage, count, scan, weighted scatter (into srec) ----
    if (tid < BKT_W) {
        deg[tid] = 0;
        int node = b * BKT_W + tid;
        sdl[tid] = (node < n) ? sv[node] : 0.f;
    }
    for (int j = tid; j < cnt; j += 256) lrec[j] = rec[base + j];
    __syncthreads();
    for (int j = tid; j < cnt; j += 256) atomicAdd(&deg[lrec[j] >> 17], 1);
    __syncthreads();
    if (tid < BKT_W) scn[tid] = deg[tid];
    __syncthreads();
    for (int off = 1; off < BKT_W; off <<= 1) {
        int t = (tid < BKT_W && tid >= off) ? scn[tid - off] : 0;
        __syncthreads();
        if (tid < BKT_W) scn[tid] += t;
        __syncthreads();
    }
    if (tid < BKT_W) cur[tid] = scn[tid] - deg[tid];
    __syncthreads();
    for (int j = tid; j < cnt; j += 256) {
        uint32_t r = lrec[j];
        int g  = r >> 17;
        int nbb = (int)(r & 0x1FFFFu);
        float e = ss[nbb] + sdl[g];
        e = (e > 0.f) ? e : 0.2f * e;
        float w = __expf(e);
        srec[atomicAdd(&cur[g], 1)] = (((uint32_t)(unsigned short)f2bf(w)) << 16) | (uint32_t)nbb;
    }
    __syncthreads();

    // ---- Phase B: each wave gathers 4 nodes; 32 edges/iter, 8 uint4 in flight ----
    int wv   = tid >> 6;         // 0..3
    int lane = tid & 63;
    int slot = lane >> 4;        // edge slot 0..3
    int c    = lane & 15;        // col chunk: cols 8c..8c+7
#pragma unroll
    for (int h = 0; h < 4; ++h) {
        int g = wv * 4 + h;
        int node = b * BKT_W + g;
        bool valid = (node < n);
        float acc[8] = {0, 0, 0, 0, 0, 0, 0, 0};
        float wsum = 0.f;
        int beg = scn[g] - deg[g];
        int dg  = valid ? deg[g] : 0;
        // first 64 edges via one LDS read + shfl distribution; 32 edges per iteration
        uint32_t rpre = (lane < dg) ? srec[beg + lane] : 0u;
        int nfull = (dg < 64) ? dg : 64;
        for (int jj = 0; jj < nfull; jj += 32) {
            uint32_t r[8];
#pragma unroll
            for (int u = 0; u < 8; ++u)
                r[u] = (uint32_t)__shfl((int)rpre, jj + 4 * u + slot);
            uint4 hrow[8];
#pragma unroll
            for (int u = 0; u < 8; ++u)
                hrow[u] = *(const uint4*)(hb + (size_t)(r[u] & 0xFFFFu) * D + c * 8);
#pragma unroll
            for (int u = 0; u < 8; ++u) {
                float w = __uint_as_float(r[u] & 0xFFFF0000u);
                wsum += w;
                const uint32_t* pq = (const uint32_t*)&hrow[u];
#pragma unroll
                for (int q = 0; q < 4; ++q) {
                    uint32_t a = pq[q];
                    acc[2 * q]     += w * __uint_as_float(a << 16);
                    acc[2 * q + 1] += w * __uint_as_float(a & 0xFFFF0000u);
                }
            }
        }
        // rare tail: dg > 64 (records still in LDS)
        for (int j = 64; j < dg; j += 16) {
            uint32_t r[4];
#pragma unroll
            for (int u = 0; u < 4; ++u) {
                int idx = j + 4 * u + slot;
                r[u] = (idx < dg) ? srec[beg + idx] : 0u;
            }
#pragma unroll
            for (int u = 0; u < 4; ++u) {
                uint4 hrow = *(const uint4*)(hb + (size_t)(r[u] & 0xFFFFu) * D + c * 8);
                float w = __uint_as_float(r[u] & 0xFFFF0000u);
                wsum += w;
                const uint32_t* pq = (const uint32_t*)&hrow;
#pragma unroll
                for (int q = 0; q < 4; ++q) {
                    uint32_t a = pq[q];
                    acc[2 * q]     += w * __uint_as_float(a << 16);
                    acc[2 * q + 1] += w * __uint_as_float(a & 0xFFFF0000u);
                }
            }
        }
        // merge 4 edge-slot groups
#pragma unroll
        for (int off = 16; off <= 32; off <<= 1) {
            wsum += __shfl_xor(wsum, off);
#pragma unroll
            for (int q = 0; q < 8; ++q) acc[q] += __shfl_xor(acc[q], off);
        }
        // lanes 0..15 finalize row and store bf16 frag-layout into T
        if (lane < 16) {
            float v[8];
            if (valid) {
                float inv = 1.0f / (wsum + 1e-16f);
                size_t o = (size_t)node * D + lane * 8;
                float4 r0 = *(const float4*)(resid + o);
                float4 r1 = *(const float4*)(resid + o + 4);
                float4 bb0 = *(const float4*)(bias + lane * 8);
                float4 bb1 = *(const float4*)(bias + lane * 8 + 4);
                v[0] = acc[0] * inv + bb0.x + r0.x;
                v[1] = acc[1] * inv + bb0.y + r0.y;
                v[2] = acc[2] * inv + bb0.z + r0.z;
                v[3] = acc[3] * inv + bb0.w + r0.w;
                v[4] = acc[4] * inv + bb1.x + r1.x;
                v[5] = acc[5] * inv + bb1.y + r1.y;
                v[6] = acc[6] * inv + bb1.z + r1.z;
                v[7] = acc[7] * inv + bb1.w + r1.w;
            } else {
#pragma unroll
                for (int m = 0; m < 8; ++m) v[m] = 0.f;
            }
#pragma unroll
            for (int half = 0; half < 2; ++half) {
                int k0 = lane * 8 + half * 4;
                int kc = k0 >> 5, hi = (k0 >> 4) & 1, g2 = (k0 >> 2) & 3;
                short4 s4;
                s4.x = f2bf(v[half * 4 + 0]);
                s4.y = f2bf(v[half * 4 + 1]);
                s4.z = f2bf(v[half * 4 + 2]);
                s4.w = f2bf(v[half * 4 + 3]);
                *(short4*)&T[g * 136 + kc * 32 + g2 * 8 + hi * 4] = s4;
            }
        }
    }
    __syncthreads();

    // ---- Phase C: 16x128 @ 128x128 MFMA epilogue; 8 col-tasks over 4 waves ----
    const bf16x8* Wf = (const bf16x8*)wpkL;
#pragma unroll
    for (int q = 0; q < 2; ++q) {
        int ct = wv * 2 + q;           // 0..7
        f32x4 acc2 = {};
#pragma unroll
        for (int kc = 0; kc < 4; ++kc) {
            bf16x8 a = *(const bf16x8*)&T[(lane & 15) * 136 + kc * 32 + (lane >> 4) * 8];
            bf16x8 bfr = Wf[(kc * 8 + ct) * 64 + lane];
            acc2 = __builtin_amdgcn_mfma_f32_16x16x32_bf16(a, bfr, acc2, 0, 0, 0);
        }
        int cbv = lane & 15, rg = lane >> 4;
        float bv = b_lin[ct * 16 + cbv];
#pragma unroll
        for (int r = 0; r < 4; ++r) {
            int grow = b * BKT_W + rg * 4 + r;
            if (grow < n) outp[(size_t)grow * D + ct * 16 + cbv] = acc2[r] + bv;
        }
    }
}

// ---------------- host ----------------
extern "C" void kernel_launch(void* const* d_in, const int* in_sizes, int n_in,
                              void* d_out, int out_size, void* d_ws, size_t ws_size,
                              hipStream_t stream) {
    const float* Xw    = (const float*)d_in[0];
    const float* Xs    = (const float*)d_in[1];
    const int*   edge  = (const int*)d_in[2];
    const float* W_s2w = (const float*)d_in[3];
    const float* as1   = (const float*)d_in[4];
    const float* ad1   = (const float*)d_in[5];
    const float* b1    = (const float*)d_in[6];
    const float* W_w2s = (const float*)d_in[7];
    const float* as2   = (const float*)d_in[8];
    const float* ad2   = (const float*)d_in[9];
    const float* b2    = (const float*)d_in[10];
    const float* W_lin = (const float*)d_in[11];
    const float* b_lin = (const float*)d_in[12];
    float* out = (float*)d_out;

    const int N  = in_sizes[0] / D;       // 20000
    const int NE = in_sizes[2] / 2;       // 640000
    const int NB = (N + BKT_W - 1) / BKT_W;
    int CAP = ((NE / NB) * 3 / 2 + 255) & ~255;
    if (CAP > CAPMAX) CAP = CAPMAX;
    const int* e_src = edge;
    const int* e_dst = edge + NE;

    char* p = (char*)d_ws;
    auto take = [&](size_t bytes) -> void* {
        p = (char*)(((uintptr_t)p + 255) & ~(uintptr_t)255);
        void* r = (void*)p;
        p += bytes;
        return r;
    };
    short* hb1  = (short*)take((size_t)N * D * 2);
    short* hb2  = (short*)take((size_t)N * D * 2);
    short* wpk1 = (short*)take((size_t)D * D * 2);
    short* wpk2 = (short*)take((size_t)D * D * 2);
    short* wpkL = (short*)take((size_t)D * D * 2);
    float* ss1  = (float*)take((size_t)N * 4);
    float* sd1  = (float*)take((size_t)N * 4);
    float* ss2  = (float*)take((size_t)N * 4);
    float* sd2  = (float*)take((size_t)N * 4);
    int*   bcur = (int*)take((size_t)2 * NB * 4);     // bcur_d | bcur_s
    int*   bcur_d = bcur;
    int*   bcur_s = bcur + NB;
    uint32_t* rec_d = (uint32_t*)take((size_t)NB * CAP * 4);
    uint32_t* rec_s = (uint32_t*)take((size_t)NB * CAP * 4);

    // 1) pack W (also zeroes bcur)
    pack_w_k<<<24, 256, 0, stream>>>(W_s2w, W_w2s, W_lin, wpk1, wpk2, wpkL, bcur, 2 * NB);

    // 2) fat: MFMA h-GEMM (both dirs) || 2-pass edge partition
    int mg = (N + RPB - 1) / RPB;
    int partGrid = (NE + 256 * EPT2 - 1) / (256 * EPT2);
    fat_h_part_k<<<2 * mg + partGrid, 256, 0, stream>>>(
        Xs, Xw, wpk1, wpk2, hb1, hb2,
        as1, as2, ad1, ad2, ss1, ss2, sd1, sd2, N, mg,
        e_src, e_dst, bcur_d, bcur_s, rec_d, rec_s, NE, CAP);

    // 3) fused: per-bucket sort + weights + gather + epilogue GEMM (dir0 first)
    bucket_gat_ep_k<<<2 * NB, 256, 0, stream>>>(
        rec_d, rec_s, bcur_d, bcur_s, ss1, sd1, ss2, sd2,
        hb1, hb2, b1, b2, Xw, Xs, wpkL, b_lin, out, N, NB, CAP);
}

// Round 17
// 86.865 us; speedup vs baseline: 1.1777x; 1.1777x over previous
//
#include <hip/hip_runtime.h>
#include <hip/hip_bf16.h>
#include <stdint.h>

#define D 128
#define BKT_W 16             // nodes per bucket
#define BKT_SH 4
#define NB_MAX 2048          // supports N <= 32768
#define RPB 128              // rows per block in MFMA h-GEMM
#define CAPMAX 1024          // per-bucket record capacity (uint32 each)
#define EPT 8

typedef __attribute__((ext_vector_type(8))) short bf16x8;
typedef __attribute__((ext_vector_type(4))) float f32x4;
typedef __attribute__((ext_vector_type(2))) float f32x2;

static __device__ __forceinline__ short f2bf(float x) {
    __hip_bfloat16 h = __float2bfloat16(x);
    return *reinterpret_cast<short*>(&h);
}

// ---------------- W pre-pack into MFMA B-fragment order (+ zero bucket cursors) ----------------
__global__ __launch_bounds__(256) void pack_w_k(const float* __restrict__ W0,
                                                const float* __restrict__ W1,
                                                const float* __restrict__ W2,
                                                short* __restrict__ P0,
                                                short* __restrict__ P1,
                                                short* __restrict__ P2,
                                                int* __restrict__ bcur, int nb2) {
    if (blockIdx.x == 0) {
        for (int i = threadIdx.x; i < nb2; i += 256) bcur[i] = 0;
    }
    int t = blockIdx.x * 256 + threadIdx.x;      // 3 * 2048 threads
    int m = t >> 11;
    int r = t & 2047;                            // (kc*8+ct)*64 + lane
    const float* W = (m == 0) ? W0 : (m == 1) ? W1 : W2;
    short*       P = (m == 0) ? P0 : (m == 1) ? P1 : P2;
    int lane = r & 63;
    int fr   = r >> 6;                           // kc*8 + ct
    int kc = fr >> 3, ct = fr & 7;
    int col = ct * 16 + (lane & 15);
    int kb  = kc * 32 + 4 * (lane >> 4);
    short v[8];
#pragma unroll
    for (int e = 0; e < 8; ++e) {
        int k = kb + (e & 3) + 16 * (e >> 2);
        v[e] = f2bf(W[k * D + col]);
    }
    short* dst = P + (size_t)r * 8;
#pragma unroll
    for (int e = 0; e < 8; ++e) dst[e] = v[e];
}

// ---------------- FAT kernel: MFMA h-GEMM (2*mg blocks) || edge partition (rest) ----------------
__global__ __launch_bounds__(256) void fat_h_part_k(
    const float* __restrict__ IN0, const float* __restrict__ IN1,
    const short* __restrict__ P0,  const short* __restrict__ P1,
    short* __restrict__ HB0, short* __restrict__ HB1,
    const float* __restrict__ as0, const float* __restrict__ as1,
    const float* __restrict__ ad0, const float* __restrict__ ad1,
    float* __restrict__ ss0, float* __restrict__ ss1,
    float* __restrict__ sd0, float* __restrict__ sd1,
    int nrows, int mg,
    const int* __restrict__ esrc, const int* __restrict__ edst,
    int* __restrict__ bcur_d, int* __restrict__ bcur_s,
    uint32_t* __restrict__ rec_d, uint32_t* __restrict__ rec_s,
    int ne, int cap) {
    __shared__ __align__(16) char smem[RPB * 136 * 2];
    int bid = blockIdx.x;
    int tid = threadIdx.x;

    if (bid < 2 * mg) {
        // ---------- MFMA h-GEMM branch ----------
        int yy = (bid >= mg) ? 1 : 0;
        int xb = bid - yy * mg;
        const float* IN = yy ? IN1 : IN0;
        const short* PK = yy ? P1  : P0;
        short*       HB = yy ? HB1 : HB0;
        const float* a_src = yy ? as1 : as0;
        const float* a_dst = yy ? ad1 : ad0;
        float* ss = yy ? ss1 : ss0;
        float* sd = yy ? sd1 : sd0;
        short* As = (short*)smem;

        int row0 = xb * RPB;
        const float4* in4 = (const float4*)IN;
#pragma unroll
        for (int i = 0; i < 16; ++i) {
            int idx = tid + i * 256;
            int row = idx >> 5;               // 32 float4 per row
            int q   = idx & 31;
            float4 v = make_float4(0.f, 0.f, 0.f, 0.f);
            int grow = row0 + row;
            if (grow < nrows) v = in4[(size_t)grow * 32 + q];
            int kc = q >> 3, hi = (q >> 2) & 1, g2 = q & 3;
            short4 s4;
            s4.x = f2bf(v.x); s4.y = f2bf(v.y); s4.z = f2bf(v.z); s4.w = f2bf(v.w);
            *(short4*)&As[row * 136 + kc * 32 + g2 * 8 + hi * 4] = s4;
        }
        __syncthreads();

        int lane = tid & 63;
        int wv   = tid >> 6;
        const bf16x8* Wf = (const bf16x8*)PK;
        f32x4 acc[2][8] = {};
#pragma unroll
        for (int kc = 0; kc < 4; ++kc) {
            bf16x8 a0 = *(const bf16x8*)&As[(wv * 32 +      (lane & 15)) * 136 + kc * 32 + (lane >> 4) * 8];
            bf16x8 a1 = *(const bf16x8*)&As[(wv * 32 + 16 + (lane & 15)) * 136 + kc * 32 + (lane >> 4) * 8];
#pragma unroll
            for (int ct = 0; ct < 8; ++ct) {
                bf16x8 b = Wf[(kc * 8 + ct) * 64 + lane];
                acc[0][ct] = __builtin_amdgcn_mfma_f32_16x16x32_bf16(a0, b, acc[0][ct], 0, 0, 0);
                acc[1][ct] = __builtin_amdgcn_mfma_f32_16x16x32_bf16(a1, b, acc[1][ct], 0, 0, 0);
            }
        }

        int cb = lane & 15, rg = lane >> 4;
        float asv[8], adv[8];
#pragma unroll
        for (int ct = 0; ct < 8; ++ct) { asv[ct] = a_src[ct * 16 + cb]; adv[ct] = a_dst[ct * 16 + cb]; }
#pragma unroll
        for (int rt = 0; rt < 2; ++rt) {
            float ssum[4] = {0, 0, 0, 0}, dsum[4] = {0, 0, 0, 0};
#pragma unroll
            for (int ct = 0; ct < 8; ++ct) {
#pragma unroll
                for (int r = 0; r < 4; ++r) {
                    float x = acc[rt][ct][r];
                    int grow = row0 + wv * 32 + rt * 16 + rg * 4 + r;
                    if (grow < nrows) HB[(size_t)grow * D + ct * 16 + cb] = f2bf(x);
                    ssum[r] += x * asv[ct];
                    dsum[r] += x * adv[ct];
                }
            }
#pragma unroll
            for (int off = 1; off < 16; off <<= 1) {
#pragma unroll
                for (int r = 0; r < 4; ++r) {
                    ssum[r] += __shfl_xor(ssum[r], off);
                    dsum[r] += __shfl_xor(dsum[r], off);
                }
            }
            if (cb == 0) {
#pragma unroll
                for (int r = 0; r < 4; ++r) {
                    int grow = row0 + wv * 32 + rt * 16 + rg * 4 + r;
                    if (grow < nrows) { ss[grow] = ssum[r]; sd[grow] = dsum[r]; }
                }
            }
        }
    } else {
        // ---------- edge partition branch ----------
        int pid = bid - 2 * mg;
        int* cnt  = (int*)smem;                       // [2][NB_MAX] = 16KB
        int* base = (int*)(smem + 2 * NB_MAX * 4);    // [2][NB_MAX] = 16KB
        int blockStart = pid * 256 * EPT;
        for (int i = tid; i < 2 * NB_MAX; i += 256) cnt[i] = 0;
        __syncthreads();
        int s[EPT], d[EPT], sl_d[EPT], sl_s[EPT];
#pragma unroll
        for (int e = 0; e < EPT; ++e) {
            int i = blockStart + e * 256 + tid;
            s[e] = -1;
            if (i < ne) {
                s[e] = esrc[i]; d[e] = edst[i];
                sl_d[e] = atomicAdd(&cnt[0 * NB_MAX + (d[e] >> BKT_SH)], 1);
                sl_s[e] = atomicAdd(&cnt[1 * NB_MAX + (s[e] >> BKT_SH)], 1);
            }
        }
        __syncthreads();
        for (int i = tid; i < 2 * NB_MAX; i += 256) {
            int a = i < NB_MAX ? i : i - NB_MAX;
            if (i < NB_MAX) {
                if (cnt[i]) base[i] = atomicAdd(&bcur_d[a], cnt[i]);
            } else {
                if (cnt[i]) base[i] = atomicAdd(&bcur_s[a], cnt[i]);
            }
        }
        __syncthreads();
#pragma unroll
        for (int e = 0; e < EPT; ++e) {
            if (s[e] >= 0) {
                int bd = d[e] >> BKT_SH, bs = s[e] >> BKT_SH;
                int od = base[0 * NB_MAX + bd] + sl_d[e];
                int os = base[1 * NB_MAX + bs] + sl_s[e];
                if (od < cap) rec_d[(size_t)bd * cap + od] = (uint32_t)s[e] | ((uint32_t)(d[e] & (BKT_W - 1)) << 17);
                if (os < cap) rec_s[(size_t)bs * cap + os] = (uint32_t)d[e] | ((uint32_t)(s[e] & (BKT_W - 1)) << 17);
            }
        }
    }
}

// ---------------- FUSED bucket sort + weights + gather + epilogue GEMM ----------------
// One block per (bucket, dir), 256 thr = 4 waves. Phase A: LDS sort + weight calc.
// Phase B: each wave gathers 4 nodes (records from LDS), packed-FMA inner loop.
// Phase C: 16x128 @ 128x128 MFMA.
__global__ __launch_bounds__(256) void bucket_gat_ep_k(
    const uint32_t* __restrict__ rec_d, const uint32_t* __restrict__ rec_s,
    const int* __restrict__ bcur_d, const int* __restrict__ bcur_s,
    const float* __restrict__ ss1, const float* __restrict__ sd1,
    const float* __restrict__ ss2, const float* __restrict__ sd2,
    const short* __restrict__ hb1, const short* __restrict__ hb2,
    const float* __restrict__ b1,  const float* __restrict__ b2,
    const float* __restrict__ Xw,  const float* __restrict__ Xs,
    const short* __restrict__ wpkL, const float* __restrict__ b_lin,
    float* __restrict__ out, int n, int nb, int cap) {

    __shared__ __align__(16) short T[BKT_W * 136];           // 4.35KB frag tile
    __shared__ uint32_t srec[CAPMAX];                        // 4KB sorted weighted records
    __shared__ uint32_t lrec[CAPMAX];                        // 4KB raw staging
    __shared__ int deg[BKT_W], scn[BKT_W], cur[BKT_W];
    __shared__ float sdl[BKT_W];

    int bid = blockIdx.x;
    int dirv = (bid >= nb) ? 1 : 0;
    int b = bid - dirv * nb;
    const uint32_t* rec  = dirv ? rec_s  : rec_d;
    const int*      bc   = dirv ? bcur_s : bcur_d;
    const float*    ss   = dirv ? ss2 : ss1;      // neighbor-side score
    const float*    sv   = dirv ? sd2 : sd1;      // self-side score
    const short*    hb   = dirv ? hb2 : hb1;
    const float*    bias = dirv ? b2  : b1;
    const float*    resid= dirv ? Xs  : Xw;
    float*          outp = out + (size_t)dirv * n * D;

    int tid = threadIdx.x;
    int cnt = bc[b]; if (cnt > cap) cnt = cap;
    size_t base = (size_t)b * cap;

    // ---- Phase A: stage, count, scan, weighted scatter (into srec) ----
    if (tid < BKT_W) {
        deg[tid] = 0;
        int node = b * BKT_W + tid;
        sdl[tid] = (node < n) ? sv[node] : 0.f;
    }
    for (int j = tid; j < cnt; j += 256) lrec[j] = rec[base + j];
    __syncthreads();
    for (int j = tid; j < cnt; j += 256) atomicAdd(&deg[lrec[j] >> 17], 1);
    __syncthreads();
    if (tid < BKT_W) scn[tid] = deg[tid];
    __syncthreads();
    for (int off = 1; off < BKT_W; off <<= 1) {
        int t = (tid < BKT_W && tid >= off) ? scn[tid - off] : 0;
        __syncthreads();
        if (tid < BKT_W) scn[tid] += t;
        __syncthreads();
    }
    if (tid < BKT_W) cur[tid] = scn[tid] - deg[tid];
    __syncthreads();
    for (int j = tid; j < cnt; j += 256) {
        uint32_t r = lrec[j];
        int g  = r >> 17;
        int nbb = (int)(r & 0x1FFFFu);
        float e = ss[nbb] + sdl[g];
        e = (e > 0.f) ? e : 0.2f * e;
        float w = __expf(e);
        srec[atomicAdd(&cur[g], 1)] = (((uint32_t)(unsigned short)f2bf(w)) << 16) | (uint32_t)nbb;
    }
    __syncthreads();   // lrec dead from here

    // ---- Phase B: each wave gathers 4 nodes; records from LDS srec; packed FMA ----
    int wv   = tid >> 6;         // 0..3
    int lane = tid & 63;
    int slot = lane >> 4;        // edge slot 0..3
    int c    = lane & 15;        // col chunk: cols 8c..8c+7
#pragma unroll
    for (int h = 0; h < 4; ++h) {
        int g = wv * 4 + h;
        int node = b * BKT_W + g;
        bool valid = (node < n);
        f32x2 acc2[4] = {};
        float wsum = 0.f;
        int beg = scn[g] - deg[g];
        int dg  = valid ? deg[g] : 0;
        // first 64 edges via one LDS read + shfl distribution
        uint32_t rpre = (lane < dg) ? srec[beg + lane] : 0u;
        int nfull = (dg < 64) ? dg : 64;
        for (int jj = 0; jj < nfull; jj += 16) {
            uint32_t r[4];
#pragma unroll
            for (int u = 0; u < 4; ++u)
                r[u] = (uint32_t)__shfl((int)rpre, jj + 4 * u + slot);
            uint4 hrow[4];
#pragma unroll
            for (int u = 0; u < 4; ++u)
                hrow[u] = *(const uint4*)(hb + (size_t)(r[u] & 0xFFFFu) * D + c * 8);
#pragma unroll
            for (int u = 0; u < 4; ++u) {
                float w = __uint_as_float(r[u] & 0xFFFF0000u);
                wsum += w;
                f32x2 wv2 = {w, w};
                const uint32_t* pq = (const uint32_t*)&hrow[u];
#pragma unroll
                for (int q = 0; q < 4; ++q) {
                    uint32_t a = pq[q];
                    f32x2 hv2 = {__uint_as_float(a << 16), __uint_as_float(a & 0xFFFF0000u)};
                    acc2[q] = __builtin_elementwise_fma(hv2, wv2, acc2[q]);
                }
            }
        }
        // rare tail: dg > 64 (records still in LDS)
        for (int j = 64; j < dg; j += 16) {
            uint32_t r[4];
#pragma unroll
            for (int u = 0; u < 4; ++u) {
                int idx = j + 4 * u + slot;
                r[u] = (idx < dg) ? srec[beg + idx] : 0u;
            }
#pragma unroll
            for (int u = 0; u < 4; ++u) {
                uint4 hrow = *(const uint4*)(hb + (size_t)(r[u] & 0xFFFFu) * D + c * 8);
                float w = __uint_as_float(r[u] & 0xFFFF0000u);
                wsum += w;
                f32x2 wv2 = {w, w};
                const uint32_t* pq = (const uint32_t*)&hrow;
#pragma unroll
                for (int q = 0; q < 4; ++q) {
                    uint32_t a = pq[q];
                    f32x2 hv2 = {__uint_as_float(a << 16), __uint_as_float(a & 0xFFFF0000u)};
                    acc2[q] = __builtin_elementwise_fma(hv2, wv2, acc2[q]);
                }
            }
        }
        // merge 4 edge-slot groups
#pragma unroll
        for (int off = 16; off <= 32; off <<= 1) {
            wsum += __shfl_xor(wsum, off);
#pragma unroll
            for (int q = 0; q < 4; ++q) {
                acc2[q].x += __shfl_xor(acc2[q].x, off);
                acc2[q].y += __shfl_xor(acc2[q].y, off);
            }
        }
        // lanes 0..15 finalize row and store bf16 frag-layout into T
        if (lane < 16) {
            float v[8];
            if (valid) {
                float inv = 1.0f / (wsum + 1e-16f);
                size_t o = (size_t)node * D + lane * 8;
                float4 r0 = *(const float4*)(resid + o);
                float4 r1 = *(const float4*)(resid + o + 4);
                float4 bb0 = *(const float4*)(bias + lane * 8);
                float4 bb1 = *(const float4*)(bias + lane * 8 + 4);
                v[0] = acc2[0].x * inv + bb0.x + r0.x;
                v[1] = acc2[0].y * inv + bb0.y + r0.y;
                v[2] = acc2[1].x * inv + bb0.z + r0.z;
                v[3] = acc2[1].y * inv + bb0.w + r0.w;
                v[4] = acc2[2].x * inv + bb1.x + r1.x;
                v[5] = acc2[2].y * inv + bb1.y + r1.y;
                v[6] = acc2[3].x * inv + bb1.z + r1.z;
                v[7] = acc2[3].y * inv + bb1.w + r1.w;
            } else {
#pragma unroll
                for (int m = 0; m < 8; ++m) v[m] = 0.f;
            }
#pragma unroll
            for (int half = 0; half < 2; ++half) {
                int k0 = lane * 8 + half * 4;
                int kc = k0 >> 5, hi = (k0 >> 4) & 1, g2 = (k0 >> 2) & 3;
                short4 s4;
                s4.x = f2bf(v[half * 4 + 0]);
                s4.y = f2bf(v[half * 4 + 1]);
                s4.z = f2bf(v[half * 4 + 2]);
                s4.w = f2bf(v[half * 4 + 3]);
                *(short4*)&T[g * 136 + kc * 32 + g2 * 8 + hi * 4] = s4;
            }
        }
    }
    __syncthreads();

    // ---- Phase C: 16x128 @ 128x128 MFMA epilogue; 8 col-tasks over 4 waves ----
    const bf16x8* Wf = (const bf16x8*)wpkL;
#pragma unroll
    for (int q = 0; q < 2; ++q) {
        int ct = wv * 2 + q;           // 0..7
        f32x4 acc = {};
#pragma unroll
        for (int kc = 0; kc < 4; ++kc) {
            bf16x8 a = *(const bf16x8*)&T[(lane & 15) * 136 + kc * 32 + (lane >> 4) * 8];
            bf16x8 bfr = Wf[(kc * 8 + ct) * 64 + lane];
            acc = __builtin_amdgcn_mfma_f32_16x16x32_bf16(a, bfr, acc, 0, 0, 0);
        }
        int cbv = lane & 15, rg = lane >> 4;
        float bv = b_lin[ct * 16 + cbv];
#pragma unroll
        for (int r = 0; r < 4; ++r) {
            int grow = b * BKT_W + rg * 4 + r;
            if (grow < n) outp[(size_t)grow * D + ct * 16 + cbv] = acc[r] + bv;
        }
    }
}

// ---------------- host ----------------
extern "C" void kernel_launch(void* const* d_in, const int* in_sizes, int n_in,
                              void* d_out, int out_size, void* d_ws, size_t ws_size,
                              hipStream_t stream) {
    const float* Xw    = (const float*)d_in[0];
    const float* Xs    = (const float*)d_in[1];
    const int*   edge  = (const int*)d_in[2];
    const float* W_s2w = (const float*)d_in[3];
    const float* as1   = (const float*)d_in[4];
    const float* ad1   = (const float*)d_in[5];
    const float* b1    = (const float*)d_in[6];
    const float* W_w2s = (const float*)d_in[7];
    const float* as2   = (const float*)d_in[8];
    const float* ad2   = (const float*)d_in[9];
    const float* b2    = (const float*)d_in[10];
    const float* W_lin = (const float*)d_in[11];
    const float* b_lin = (const float*)d_in[12];
    float* out = (float*)d_out;

    const int N  = in_sizes[0] / D;       // 20000
    const int NE = in_sizes[2] / 2;       // 640000
    const int NB = (N + BKT_W - 1) / BKT_W;
    int CAP = ((NE / NB) * 3 / 2 + 255) & ~255;
    if (CAP > CAPMAX) CAP = CAPMAX;
    const int* e_src = edge;
    const int* e_dst = edge + NE;

    char* p = (char*)d_ws;
    auto take = [&](size_t bytes) -> void* {
        p = (char*)(((uintptr_t)p + 255) & ~(uintptr_t)255);
        void* r = (void*)p;
        p += bytes;
        return r;
    };
    short* hb1  = (short*)take((size_t)N * D * 2);
    short* hb2  = (short*)take((size_t)N * D * 2);
    short* wpk1 = (short*)take((size_t)D * D * 2);
    short* wpk2 = (short*)take((size_t)D * D * 2);
    short* wpkL = (short*)take((size_t)D * D * 2);
    float* ss1  = (float*)take((size_t)N * 4);
    float* sd1  = (float*)take((size_t)N * 4);
    float* ss2  = (float*)take((size_t)N * 4);
    float* sd2  = (float*)take((size_t)N * 4);
    int*   bcur = (int*)take((size_t)2 * NB * 4);     // bcur_d | bcur_s
    int*   bcur_d = bcur;
    int*   bcur_s = bcur + NB;
    uint32_t* rec_d = (uint32_t*)take((size_t)NB * CAP * 4);
    uint32_t* rec_s = (uint32_t*)take((size_t)NB * CAP * 4);

    // 1) pack W (also zeroes bcur)
    pack_w_k<<<24, 256, 0, stream>>>(W_s2w, W_w2s, W_lin, wpk1, wpk2, wpkL, bcur, 2 * NB);

    // 2) fat: MFMA h-GEMM (both dirs) || edge partition
    int mg = (N + RPB - 1) / RPB;
    int partGrid = (NE + 256 * EPT - 1) / (256 * EPT);
    fat_h_part_k<<<2 * mg + partGrid, 256, 0, stream>>>(
        Xs, Xw, wpk1, wpk2, hb1, hb2,
        as1, as2, ad1, ad2, ss1, ss2, sd1, sd2, N, mg,
        e_src, e_dst, bcur_d, bcur_s, rec_d, rec_s, NE, CAP);

    // 3) fused: per-bucket sort + weights + gather + epilogue GEMM (dir0 first)
    bucket_gat_ep_k<<<2 * NB, 256, 0, stream>>>(
        rec_d, rec_s, bcur_d, bcur_s, ss1, sd1, ss2, sd2,
        hb1, hb2, b1, b2, Xw, Xs, wpkL, b_lin, out, N, NB, CAP);
}

// Round 18
// 83.550 us; speedup vs baseline: 1.2244x; 1.0397x over previous
//
#include <hip/hip_runtime.h>
#include <hip/hip_bf16.h>
#include <stdint.h>

#define D 128
#define BKT_W 16             // nodes per bucket
#define BKT_SH 4
#define NB_MAX 2048          // supports N <= 32768
#define RPB 128              // rows per block in MFMA h-GEMM
#define CAPMAX 1024          // per-bucket record capacity (uint32 each)
#define EPT 8

typedef __attribute__((ext_vector_type(8))) short bf16x8;
typedef __attribute__((ext_vector_type(4))) float f32x4;

static __device__ __forceinline__ short f2bf(float x) {
    __hip_bfloat16 h = __float2bfloat16(x);
    return *reinterpret_cast<short*>(&h);
}

// ---------------- W pre-pack into MFMA B-fragment order (+ zero bucket cursors) ----------------
__global__ __launch_bounds__(256) void pack_w_k(const float* __restrict__ W0,
                                                const float* __restrict__ W1,
                                                const float* __restrict__ W2,
                                                short* __restrict__ P0,
                                                short* __restrict__ P1,
                                                short* __restrict__ P2,
                                                int* __restrict__ bcur, int nb2) {
    if (blockIdx.x == 0) {
        for (int i = threadIdx.x; i < nb2; i += 256) bcur[i] = 0;
    }
    int t = blockIdx.x * 256 + threadIdx.x;      // 3 * 2048 threads
    int m = t >> 11;
    int r = t & 2047;                            // (kc*8+ct)*64 + lane
    const float* W = (m == 0) ? W0 : (m == 1) ? W1 : W2;
    short*       P = (m == 0) ? P0 : (m == 1) ? P1 : P2;
    int lane = r & 63;
    int fr   = r >> 6;                           // kc*8 + ct
    int kc = fr >> 3, ct = fr & 7;
    int col = ct * 16 + (lane & 15);
    int kb  = kc * 32 + 4 * (lane >> 4);
    short v[8];
#pragma unroll
    for (int e = 0; e < 8; ++e) {
        int k = kb + (e & 3) + 16 * (e >> 2);
        v[e] = f2bf(W[k * D + col]);
    }
    short* dst = P + (size_t)r * 8;
#pragma unroll
    for (int e = 0; e < 8; ++e) dst[e] = v[e];
}

// ---------------- FAT kernel: MFMA h-GEMM (2*mg blocks) || edge partition (rest) ----------------
__global__ __launch_bounds__(256) void fat_h_part_k(
    const float* __restrict__ IN0, const float* __restrict__ IN1,
    const short* __restrict__ P0,  const short* __restrict__ P1,
    short* __restrict__ HB0, short* __restrict__ HB1,
    const float* __restrict__ as0, const float* __restrict__ as1,
    const float* __restrict__ ad0, const float* __restrict__ ad1,
    float* __restrict__ ss0, float* __restrict__ ss1,
    float* __restrict__ sd0, float* __restrict__ sd1,
    int nrows, int mg,
    const int* __restrict__ esrc, const int* __restrict__ edst,
    int* __restrict__ bcur_d, int* __restrict__ bcur_s,
    uint32_t* __restrict__ rec_d, uint32_t* __restrict__ rec_s,
    int ne, int cap) {
    __shared__ __align__(16) char smem[RPB * 136 * 2];
    int bid = blockIdx.x;
    int tid = threadIdx.x;

    if (bid < 2 * mg) {
        // ---------- MFMA h-GEMM branch ----------
        int yy = (bid >= mg) ? 1 : 0;
        int xb = bid - yy * mg;
        const float* IN = yy ? IN1 : IN0;
        const short* PK = yy ? P1  : P0;
        short*       HB = yy ? HB1 : HB0;
        const float* a_src = yy ? as1 : as0;
        const float* a_dst = yy ? ad1 : ad0;
        float* ss = yy ? ss1 : ss0;
        float* sd = yy ? sd1 : sd0;
        short* As = (short*)smem;

        int row0 = xb * RPB;
        const float4* in4 = (const float4*)IN;
#pragma unroll
        for (int i = 0; i < 16; ++i) {
            int idx = tid + i * 256;
            int row = idx >> 5;               // 32 float4 per row
            int q   = idx & 31;
            float4 v = make_float4(0.f, 0.f, 0.f, 0.f);
            int grow = row0 + row;
            if (grow < nrows) v = in4[(size_t)grow * 32 + q];
            int kc = q >> 3, hi = (q >> 2) & 1, g2 = q & 3;
            short4 s4;
            s4.x = f2bf(v.x); s4.y = f2bf(v.y); s4.z = f2bf(v.z); s4.w = f2bf(v.w);
            *(short4*)&As[row * 136 + kc * 32 + g2 * 8 + hi * 4] = s4;
        }
        __syncthreads();

        int lane = tid & 63;
        int wv   = tid >> 6;
        const bf16x8* Wf = (const bf16x8*)PK;
        f32x4 acc[2][8] = {};
#pragma unroll
        for (int kc = 0; kc < 4; ++kc) {
            bf16x8 a0 = *(const bf16x8*)&As[(wv * 32 +      (lane & 15)) * 136 + kc * 32 + (lane >> 4) * 8];
            bf16x8 a1 = *(const bf16x8*)&As[(wv * 32 + 16 + (lane & 15)) * 136 + kc * 32 + (lane >> 4) * 8];
#pragma unroll
            for (int ct = 0; ct < 8; ++ct) {
                bf16x8 b = Wf[(kc * 8 + ct) * 64 + lane];
                acc[0][ct] = __builtin_amdgcn_mfma_f32_16x16x32_bf16(a0, b, acc[0][ct], 0, 0, 0);
                acc[1][ct] = __builtin_amdgcn_mfma_f32_16x16x32_bf16(a1, b, acc[1][ct], 0, 0, 0);
            }
        }

        int cb = lane & 15, rg = lane >> 4;
        float asv[8], adv[8];
#pragma unroll
        for (int ct = 0; ct < 8; ++ct) { asv[ct] = a_src[ct * 16 + cb]; adv[ct] = a_dst[ct * 16 + cb]; }
#pragma unroll
        for (int rt = 0; rt < 2; ++rt) {
            float ssum[4] = {0, 0, 0, 0}, dsum[4] = {0, 0, 0, 0};
#pragma unroll
            for (int ct = 0; ct < 8; ++ct) {
#pragma unroll
                for (int r = 0; r < 4; ++r) {
                    float x = acc[rt][ct][r];
                    int grow = row0 + wv * 32 + rt * 16 + rg * 4 + r;
                    if (grow < nrows) HB[(size_t)grow * D + ct * 16 + cb] = f2bf(x);
                    ssum[r] += x * asv[ct];
                    dsum[r] += x * adv[ct];
                }
            }
#pragma unroll
            for (int off = 1; off < 16; off <<= 1) {
#pragma unroll
                for (int r = 0; r < 4; ++r) {
                    ssum[r] += __shfl_xor(ssum[r], off);
                    dsum[r] += __shfl_xor(dsum[r], off);
                }
            }
            if (cb == 0) {
#pragma unroll
                for (int r = 0; r < 4; ++r) {
                    int grow = row0 + wv * 32 + rt * 16 + rg * 4 + r;
                    if (grow < nrows) { ss[grow] = ssum[r]; sd[grow] = dsum[r]; }
                }
            }
        }
    } else {
        // ---------- edge partition branch ----------
        int pid = bid - 2 * mg;
        int* cnt  = (int*)smem;                       // [2][NB_MAX] = 16KB
        int* base = (int*)(smem + 2 * NB_MAX * 4);    // [2][NB_MAX] = 16KB
        int blockStart = pid * 256 * EPT;
        for (int i = tid; i < 2 * NB_MAX; i += 256) cnt[i] = 0;
        __syncthreads();
        int s[EPT], d[EPT], sl_d[EPT], sl_s[EPT];
#pragma unroll
        for (int e = 0; e < EPT; ++e) {
            int i = blockStart + e * 256 + tid;
            s[e] = -1;
            if (i < ne) {
                s[e] = esrc[i]; d[e] = edst[i];
                sl_d[e] = atomicAdd(&cnt[0 * NB_MAX + (d[e] >> BKT_SH)], 1);
                sl_s[e] = atomicAdd(&cnt[1 * NB_MAX + (s[e] >> BKT_SH)], 1);
            }
        }
        __syncthreads();
        for (int i = tid; i < 2 * NB_MAX; i += 256) {
            int a = i < NB_MAX ? i : i - NB_MAX;
            if (i < NB_MAX) {
                if (cnt[i]) base[i] = atomicAdd(&bcur_d[a], cnt[i]);
            } else {
                if (cnt[i]) base[i] = atomicAdd(&bcur_s[a], cnt[i]);
            }
        }
        __syncthreads();
#pragma unroll
        for (int e = 0; e < EPT; ++e) {
            if (s[e] >= 0) {
                int bd = d[e] >> BKT_SH, bs = s[e] >> BKT_SH;
                int od = base[0 * NB_MAX + bd] + sl_d[e];
                int os = base[1 * NB_MAX + bs] + sl_s[e];
                if (od < cap) rec_d[(size_t)bd * cap + od] = (uint32_t)s[e] | ((uint32_t)(d[e] & (BKT_W - 1)) << 17);
                if (os < cap) rec_s[(size_t)bs * cap + os] = (uint32_t)d[e] | ((uint32_t)(s[e] & (BKT_W - 1)) << 17);
            }
        }
    }
}

// ---------------- FUSED bucket sort + weights + gather + epilogue GEMM ----------------
// One block per (bucket, dir), 256 thr = 4 waves. Phase A: LDS sort + weight calc.
// Phase B: each wave gathers 4 nodes (records from LDS). Phase C: 16x128 @ 128x128 MFMA.
__global__ __launch_bounds__(256) void bucket_gat_ep_k(
    const uint32_t* __restrict__ rec_d, const uint32_t* __restrict__ rec_s,
    const int* __restrict__ bcur_d, const int* __restrict__ bcur_s,
    const float* __restrict__ ss1, const float* __restrict__ sd1,
    const float* __restrict__ ss2, const float* __restrict__ sd2,
    const short* __restrict__ hb1, const short* __restrict__ hb2,
    const float* __restrict__ b1,  const float* __restrict__ b2,
    const float* __restrict__ Xw,  const float* __restrict__ Xs,
    const short* __restrict__ wpkL, const float* __restrict__ b_lin,
    float* __restrict__ out, int n, int nb, int cap) {

    __shared__ __align__(16) short T[BKT_W * 136];           // 4.35KB frag tile
    __shared__ uint32_t srec[CAPMAX];                        // 4KB sorted weighted records
    __shared__ uint32_t lrec[CAPMAX];                        // 4KB raw staging
    __shared__ int deg[BKT_W], scn[BKT_W], cur[BKT_W];
    __shared__ float sdl[BKT_W];

    int bid = blockIdx.x;
    int dirv = (bid >= nb) ? 1 : 0;
    int b = bid - dirv * nb;
    const uint32_t* rec  = dirv ? rec_s  : rec_d;
    const int*      bc   = dirv ? bcur_s : bcur_d;
    const float*    ss   = dirv ? ss2 : ss1;      // neighbor-side score
    const float*    sv   = dirv ? sd2 : sd1;      // self-side score
    const short*    hb   = dirv ? hb2 : hb1;
    const float*    bias = dirv ? b2  : b1;
    const float*    resid= dirv ? Xs  : Xw;
    float*          outp = out + (size_t)dirv * n * D;

    int tid = threadIdx.x;
    int cnt = bc[b]; if (cnt > cap) cnt = cap;
    size_t base = (size_t)b * cap;

    // ---- Phase A: stage, count, scan, weighted scatter (into srec) ----
    if (tid < BKT_W) {
        deg[tid] = 0;
        int node = b * BKT_W + tid;
        sdl[tid] = (node < n) ? sv[node] : 0.f;
    }
    for (int j = tid; j < cnt; j += 256) lrec[j] = rec[base + j];
    __syncthreads();
    for (int j = tid; j < cnt; j += 256) atomicAdd(&deg[lrec[j] >> 17], 1);
    __syncthreads();
    if (tid < BKT_W) scn[tid] = deg[tid];
    __syncthreads();
    for (int off = 1; off < BKT_W; off <<= 1) {
        int t = (tid < BKT_W && tid >= off) ? scn[tid - off] : 0;
        __syncthreads();
        if (tid < BKT_W) scn[tid] += t;
        __syncthreads();
    }
    if (tid < BKT_W) cur[tid] = scn[tid] - deg[tid];
    __syncthreads();
    for (int j = tid; j < cnt; j += 256) {
        uint32_t r = lrec[j];
        int g  = r >> 17;
        int nbb = (int)(r & 0x1FFFFu);
        float e = ss[nbb] + sdl[g];
        e = (e > 0.f) ? e : 0.2f * e;
        float w = __expf(e);
        srec[atomicAdd(&cur[g], 1)] = (((uint32_t)(unsigned short)f2bf(w)) << 16) | (uint32_t)nbb;
    }
    __syncthreads();   // lrec dead from here

    // ---- Phase B: each wave gathers 4 nodes; records from LDS srec ----
    int wv   = tid >> 6;         // 0..3
    int lane = tid & 63;
    int slot = lane >> 4;        // edge slot 0..3
    int c    = lane & 15;        // col chunk: cols 8c..8c+7
#pragma unroll
    for (int h = 0; h < 4; ++h) {
        int g = wv * 4 + h;
        int node = b * BKT_W + g;
        bool valid = (node < n);
        float acc[8] = {0, 0, 0, 0, 0, 0, 0, 0};
        float wsum = 0.f;
        int beg = scn[g] - deg[g];
        int dg  = valid ? deg[g] : 0;
        // first 64 edges via one LDS read + shfl distribution
        uint32_t rpre = (lane < dg) ? srec[beg + lane] : 0u;
        int nfull = (dg < 64) ? dg : 64;
        for (int jj = 0; jj < nfull; jj += 16) {
            uint32_t r[4];
#pragma unroll
            for (int u = 0; u < 4; ++u)
                r[u] = (uint32_t)__shfl((int)rpre, jj + 4 * u + slot);
            uint4 hrow[4];
#pragma unroll
            for (int u = 0; u < 4; ++u)
                hrow[u] = *(const uint4*)(hb + (size_t)(r[u] & 0xFFFFu) * D + c * 8);
#pragma unroll
            for (int u = 0; u < 4; ++u) {
                float w = __uint_as_float(r[u] & 0xFFFF0000u);
                wsum += w;
                const uint32_t* pq = (const uint32_t*)&hrow[u];
#pragma unroll
                for (int q = 0; q < 4; ++q) {
                    uint32_t a = pq[q];
                    acc[2 * q]     += w * __uint_as_float(a << 16);
                    acc[2 * q + 1] += w * __uint_as_float(a & 0xFFFF0000u);
                }
            }
        }
        // rare tail: dg > 64 (records still in LDS)
        for (int j = 64; j < dg; j += 16) {
            uint32_t r[4];
#pragma unroll
            for (int u = 0; u < 4; ++u) {
                int idx = j + 4 * u + slot;
                r[u] = (idx < dg) ? srec[beg + idx] : 0u;
            }
#pragma unroll
            for (int u = 0; u < 4; ++u) {
                uint4 hrow = *(const uint4*)(hb + (size_t)(r[u] & 0xFFFFu) * D + c * 8);
                float w = __uint_as_float(r[u] & 0xFFFF0000u);
                wsum += w;
                const uint32_t* pq = (const uint32_t*)&hrow;
#pragma unroll
                for (int q = 0; q < 4; ++q) {
                    uint32_t a = pq[q];
                    acc[2 * q]     += w * __uint_as_float(a << 16);
                    acc[2 * q + 1] += w * __uint_as_float(a & 0xFFFF0000u);
                }
            }
        }
        // merge 4 edge-slot groups
#pragma unroll
        for (int off = 16; off <= 32; off <<= 1) {
            wsum += __shfl_xor(wsum, off);
#pragma unroll
            for (int q = 0; q < 8; ++q) acc[q] += __shfl_xor(acc[q], off);
        }
        // lanes 0..15 finalize row and store bf16 frag-layout into T
        if (lane < 16) {
            float v[8];
            if (valid) {
                float inv = 1.0f / (wsum + 1e-16f);
                size_t o = (size_t)node * D + lane * 8;
                float4 r0 = *(const float4*)(resid + o);
                float4 r1 = *(const float4*)(resid + o + 4);
                float4 bb0 = *(const float4*)(bias + lane * 8);
                float4 bb1 = *(const float4*)(bias + lane * 8 + 4);
                v[0] = acc[0] * inv + bb0.x + r0.x;
                v[1] = acc[1] * inv + bb0.y + r0.y;
                v[2] = acc[2] * inv + bb0.z + r0.z;
                v[3] = acc[3] * inv + bb0.w + r0.w;
                v[4] = acc[4] * inv + bb1.x + r1.x;
                v[5] = acc[5] * inv + bb1.y + r1.y;
                v[6] = acc[6] * inv + bb1.z + r1.z;
                v[7] = acc[7] * inv + bb1.w + r1.w;
            } else {
#pragma unroll
                for (int m = 0; m < 8; ++m) v[m] = 0.f;
            }
#pragma unroll
            for (int half = 0; half < 2; ++half) {
                int k0 = lane * 8 + half * 4;
                int kc = k0 >> 5, hi = (k0 >> 4) & 1, g2 = (k0 >> 2) & 3;
                short4 s4;
                s4.x = f2bf(v[half * 4 + 0]);
                s4.y = f2bf(v[half * 4 + 1]);
                s4.z = f2bf(v[half * 4 + 2]);
                s4.w = f2bf(v[half * 4 + 3]);
                *(short4*)&T[g * 136 + kc * 32 + g2 * 8 + hi * 4] = s4;
            }
        }
    }
    __syncthreads();

    // ---- Phase C: 16x128 @ 128x128 MFMA epilogue; 8 col-tasks over 4 waves ----
    const bf16x8* Wf = (const bf16x8*)wpkL;
#pragma unroll
    for (int q = 0; q < 2; ++q) {
        int ct = wv * 2 + q;           // 0..7
        f32x4 acc2 = {};
#pragma unroll
        for (int kc = 0; kc < 4; ++kc) {
            bf16x8 a = *(const bf16x8*)&T[(lane & 15) * 136 + kc * 32 + (lane >> 4) * 8];
            bf16x8 bfr = Wf[(kc * 8 + ct) * 64 + lane];
            acc2 = __builtin_amdgcn_mfma_f32_16x16x32_bf16(a, bfr, acc2, 0, 0, 0);
        }
        int cb = lane & 15, rg = lane >> 4;
        float bv = b_lin[ct * 16 + cb];
#pragma unroll
        for (int r = 0; r < 4; ++r) {
            int grow = b * BKT_W + rg * 4 + r;
            if (grow < n) outp[(size_t)grow * D + ct * 16 + cb] = acc2[r] + bv;
        }
    }
}

// ---------------- host ----------------
extern "C" void kernel_launch(void* const* d_in, const int* in_sizes, int n_in,
                              void* d_out, int out_size, void* d_ws, size_t ws_size,
                              hipStream_t stream) {
    const float* Xw    = (const float*)d_in[0];
    const float* Xs    = (const float*)d_in[1];
    const int*   edge  = (const int*)d_in[2];
    const float* W_s2w = (const float*)d_in[3];
    const float* as1   = (const float*)d_in[4];
    const float* ad1   = (const float*)d_in[5];
    const float* b1    = (const float*)d_in[6];
    const float* W_w2s = (const float*)d_in[7];
    const float* as2   = (const float*)d_in[8];
    const float* ad2   = (const float*)d_in[9];
    const float* b2    = (const float*)d_in[10];
    const float* W_lin = (const float*)d_in[11];
    const float* b_lin = (const float*)d_in[12];
    float* out = (float*)d_out;

    const int N  = in_sizes[0] / D;       // 20000
    const int NE = in_sizes[2] / 2;       // 640000
    const int NB = (N + BKT_W - 1) / BKT_W;
    int CAP = ((NE / NB) * 3 / 2 + 255) & ~255;
    if (CAP > CAPMAX) CAP = CAPMAX;
    const int* e_src = edge;
    const int* e_dst = edge + NE;

    char* p = (char*)d_ws;
    auto take = [&](size_t bytes) -> void* {
        p = (char*)(((uintptr_t)p + 255) & ~(uintptr_t)255);
        void* r = (void*)p;
        p += bytes;
        return r;
    };
    short* hb1  = (short*)take((size_t)N * D * 2);
    short* hb2  = (short*)take((size_t)N * D * 2);
    short* wpk1 = (short*)take((size_t)D * D * 2);
    short* wpk2 = (short*)take((size_t)D * D * 2);
    short* wpkL = (short*)take((size_t)D * D * 2);
    float* ss1  = (float*)take((size_t)N * 4);
    float* sd1  = (float*)take((size_t)N * 4);
    float* ss2  = (float*)take((size_t)N * 4);
    float* sd2  = (float*)take((size_t)N * 4);
    int*   bcur = (int*)take((size_t)2 * NB * 4);     // bcur_d | bcur_s
    int*   bcur_d = bcur;
    int*   bcur_s = bcur + NB;
    uint32_t* rec_d = (uint32_t*)take((size_t)NB * CAP * 4);
    uint32_t* rec_s = (uint32_t*)take((size_t)NB * CAP * 4);

    // 1) pack W (also zeroes bcur)
    pack_w_k<<<24, 256, 0, stream>>>(W_s2w, W_w2s, W_lin, wpk1, wpk2, wpkL, bcur, 2 * NB);

    // 2) fat: MFMA h-GEMM (both dirs) || edge partition
    int mg = (N + RPB - 1) / RPB;
    int partGrid = (NE + 256 * EPT - 1) / (256 * EPT);
    fat_h_part_k<<<2 * mg + partGrid, 256, 0, stream>>>(
        Xs, Xw, wpk1, wpk2, hb1, hb2,
        as1, as2, ad1, ad2, ss1, ss2, sd1, sd2, N, mg,
        e_src, e_dst, bcur_d, bcur_s, rec_d, rec_s, NE, CAP);

    // 3) fused: per-bucket sort + weights + gather + epilogue GEMM (dir0 first)
    bucket_gat_ep_k<<<2 * NB, 256, 0, stream>>>(
        rec_d, rec_s, bcur_d, bcur_s, ss1, sd1, ss2, sd2,
        hb1, hb2, b1, b2, Xw, Xs, wpkL, b_lin, out, N, NB, CAP);
}